// Round 13
// baseline (93.604 us; speedup 1.0000x reference)
//
#include <hip/hip_runtime.h>
#include <hip/hip_bf16.h>

#define S_LEN 4096
#define NH 16
#define HD 64
#define WIN 33
#define PAD 16
#define QT 64
#define KROWS 96
#define KPITCH_U 36   // uints per LDS row (72 shorts = 144B, breaks bank conflicts)

typedef short short8 __attribute__((ext_vector_type(8)));
typedef float f32x4 __attribute__((ext_vector_type(4)));

__device__ __forceinline__ float bl(unsigned u){ return __uint_as_float(u << 16); }
__device__ __forceinline__ float bh(unsigned u){ return __uint_as_float(u & 0xffff0000u); }
__device__ __forceinline__ unsigned f2bfu(float f){
  unsigned u = __float_as_uint(f);
  return (u + 0x7fffu + ((u >> 16) & 1u)) >> 16;   // RNE
}
__device__ __forceinline__ unsigned pack2(float a, float b){ return f2bfu(a) | (f2bfu(b) << 16); }

__device__ __forceinline__ void gload_lds16(const void* g, void* l){
  __builtin_amdgcn_global_load_lds(
      (const __attribute__((address_space(1))) void*)g,
      (__attribute__((address_space(3))) void*)l, 16, 0, 0);
}

// ---------------- fused prep kernel ----------------
// b in [0,512): rope float2 table; [512,2560): x->bf16; [2560,5632): W_qkv^T; [5632,6656): W_out^T

__global__ __launch_bounds__(256) void prep_all(
    const float* __restrict__ rot, float2* __restrict__ csq,
    const float* __restrict__ x, __hip_bfloat16* __restrict__ xb,
    const float* __restrict__ Wq, __hip_bfloat16* __restrict__ Wt1,
    const float* __restrict__ Wo, __hip_bfloat16* __restrict__ Wt2)
{
  __shared__ float tile[32][33];
  const int b = blockIdx.x, tid = threadIdx.x;
  if (b < 512) {
    int t = b * 256 + tid;                 // 131072 = 4096*32 exactly
    float v = rot[t], sv, cv;
    __sincosf(v, &sv, &cv);
    csq[t] = make_float2(cv, sv);
  } else if (b < 2560) {
    int t = (b - 512) * 256 + tid;         // one thread = 8 elements
    const float4* p = (const float4*)x + (size_t)t * 2;
    float4 a = p[0], c = p[1];
    uint4 o;
    o.x = pack2(a.x, a.y); o.y = pack2(a.z, a.w);
    o.z = pack2(c.x, c.y); o.w = pack2(c.z, c.w);
    ((uint4*)xb)[t] = o;
  } else {
    const float* in; unsigned short* out; int R, C, bx, by;
    if (b < 5632) { int bb = b - 2560; in = Wq; out = (unsigned short*)Wt1; R = 1024; C = 3072; bx = bb % 96; by = bb / 96; }
    else          { int bb = b - 5632; in = Wo; out = (unsigned short*)Wt2; R = 1024; C = 1024; bx = bb % 32; by = bb / 32; }
    int c0 = bx * 32, r0 = by * 32;
    int tx = tid & 31, ty = tid >> 5;
    #pragma unroll
    for (int i = 0; i < 4; ++i) {
      int r = ty + i * 8;
      tile[r][tx] = in[(size_t)(r0 + r) * C + c0 + tx];
    }
    __syncthreads();
    #pragma unroll
    for (int i = 0; i < 4; ++i) {
      int cc = ty + i * 8;
      out[(size_t)(c0 + cc) * R + r0 + tx] = (unsigned short)f2bfu(tile[tx][cc]);
    }
  }
}

// ------- GEMM1: 256x256 tile, 512 thr / 8 waves (wave-tile 128x64), BK=64, 4-phase
//         schedule: bulk 8-load prefetch at p0, vmcnt(0) only at K-tile boundary,
//         phase-locked raw barriers + setprio, A-frag reuse, bias+RoPE epilogue -------

__global__ __launch_bounds__(512) void gemm_qkv_rope(
    const __hip_bfloat16* __restrict__ A,    // [M][K]  x (bf16)
    const __hip_bfloat16* __restrict__ Bt,   // [N][K]  W_qkv^T (bf16)
    const float* __restrict__ bias,          // [N]
    const float2* __restrict__ csq,          // [S][32] (cos,sin)
    unsigned short* __restrict__ Cout,       // bf16 [M][N]
    int M, int N, int K)
{
  __shared__ short lds[2][2][2][128][64];    // [buf][mat A=0/B=1][half][row][col] = 128 KB
  const int tid = threadIdx.x;
  const int wave = tid >> 6, lane = tid & 63;
  const int m0 = blockIdx.y * 256, n0 = blockIdx.x * 256;
  const int wm = (wave >> 2) * 128, wn = (wave & 3) * 64;   // 2m x 4n wave grid
  const int l16 = lane >> 4, l15 = lane & 15;
  const int halfA = wave >> 2;               // A-half this wave reads (rows wm..wm+127)
  const int halfB = (wave >> 1) & 1;         // B-half this wave reads (wn>=128)
  const int rBbase = (wn & 64);              // B row base within its half

  f32x4 acc[8][4];
  #pragma unroll
  for (int i = 0; i < 8; ++i)
    #pragma unroll
    for (int j = 0; j < 4; ++j) acc[i][j] = (f32x4){0.f, 0.f, 0.f, 0.f};

  // stage one half-tile (128 rows x 64 cols bf16 = 16 KB): 2 loads/thread.
  // linear LDS dest, inverse-swizzled global source (rule #21).
  auto stage_ht = [&](int buf, int kt, int mat, int h) {
    const __hip_bfloat16* src = mat ? Bt : A;
    const int base = mat ? n0 : m0;
    #pragma unroll
    for (int it = 0; it < 2; ++it) {
      const int c = it * 512 + tid;          // 0..1023 chunks of 16B
      const int r = c >> 3, s8 = c & 7;
      const int ss = s8 ^ (r & 7);
      gload_lds16(src + (size_t)(base + h * 128 + r) * K + kt * 64 + ss * 8,
                  (char*)&lds[buf][mat][h][0][0] + c * 16);
    }
  };
  auto stage_tile = [&](int buf, int kt) {
    stage_ht(buf, kt, 0, 0); stage_ht(buf, kt, 0, 1);
    stage_ht(buf, kt, 1, 0); stage_ht(buf, kt, 1, 1);
  };

  const int nkt = K / 64;   // 16
  stage_tile(0, 0);
  asm volatile("s_waitcnt vmcnt(0)" ::: "memory");
  __builtin_amdgcn_s_barrier();

  for (int kt = 0; kt < nkt; ++kt) {
    const int cur = kt & 1;
    const bool pf = (kt + 1 < nkt);
    short8 af[4][2];                         // A-frags, live across phase pairs
    #pragma unroll
    for (int p = 0; p < 4; ++p) {
      const int mh = p >> 1, nq = p & 1;
      if (nq == 0) {                         // read A-frags once per m-half (8 ds_read_b128)
        #pragma unroll
        for (int mi = 0; mi < 4; ++mi)
          #pragma unroll
          for (int ks = 0; ks < 2; ++ks) {
            const int r = mh * 64 + mi * 16 + l15;
            const int slot = (ks * 4 + l16) ^ (r & 7);
            af[mi][ks] = *(const short8*)&lds[cur][0][halfA][r][slot * 8];
          }
      }
      short8 bf[2][2];                       // B-frags each phase (4 ds_read_b128)
      #pragma unroll
      for (int ni = 0; ni < 2; ++ni)
        #pragma unroll
        for (int ks = 0; ks < 2; ++ks) {
          const int r = rBbase + nq * 32 + ni * 16 + l15;
          const int slot = (ks * 4 + l16) ^ (r & 7);
          bf[ni][ks] = *(const short8*)&lds[cur][1][halfB][r][slot * 8];
        }
      if (p == 0 && pf) stage_tile(cur ^ 1, kt + 1);   // bulk prefetch: 8 loads, ~3.5 phases to land
      __builtin_amdgcn_sched_barrier(0);
      __builtin_amdgcn_s_barrier();          // phase-entry lockstep (all ds_reads/stages issued)
      __builtin_amdgcn_s_setprio(1);
      #pragma unroll
      for (int ks = 0; ks < 2; ++ks)
        #pragma unroll
        for (int mi = 0; mi < 4; ++mi)
          #pragma unroll
          for (int ni = 0; ni < 2; ++ni)
            acc[mh * 4 + mi][nq * 2 + ni] =
                __builtin_amdgcn_mfma_f32_16x16x32_bf16(af[mi][ks], bf[ni][ks],
                                                        acc[mh * 4 + mi][nq * 2 + ni], 0, 0, 0);
      __builtin_amdgcn_s_setprio(0);
      __builtin_amdgcn_sched_barrier(0);
      if (p == 3 && pf) asm volatile("s_waitcnt vmcnt(0)" ::: "memory");  // next tile landed
      __builtin_amdgcn_s_barrier();          // phase-exit: reads of cur done / next-tile gate
    }
  }

  // epilogue: C/D layout col=lane&15, row=(lane>>4)*4+reg.
  // cols: rseg = cn%192: q [0,64) k [64,128) v [128,192); RoPE pair via shfl_xor(1).
  #pragma unroll
  for (int bj = 0; bj < 4; ++bj) {
    const int cn = n0 + wn + bj * 16 + l15;
    const int rseg = cn % 192;               // wave-uniform per bj (16-col groups don't straddle)
    const float bv = bias[cn];
    if (rseg < 128) {                        // q or k -> RoPE
      const int i = (rseg & 63) >> 1;
      const float sgn = (cn & 1) ? 1.f : -1.f;
      #pragma unroll
      for (int ai = 0; ai < 8; ++ai) {
        #pragma unroll
        for (int j = 0; j < 4; ++j) {
          const int rm = m0 + wm + ai * 16 + l16 * 4 + j;
          const float v = acc[ai][bj][j] + bv;
          const float p = __shfl_xor(v, 1);
          const float2 cs = csq[rm * 32 + i];
          Cout[(size_t)rm * N + cn] = (unsigned short)f2bfu(v * cs.x + p * (sgn * cs.y));
        }
      }
    } else {
      #pragma unroll
      for (int ai = 0; ai < 8; ++ai) {
        #pragma unroll
        for (int j = 0; j < 4; ++j) {
          const int rm = m0 + wm + ai * 16 + l16 * 4 + j;
          Cout[(size_t)rm * N + cn] = (unsigned short)f2bfu(acc[ai][bj][j] + bv);
        }
      }
    }
  }
}

// ------- GEMM2: 64x64 tile, BK=64, double-buffered 32 KB LDS, counted vmcnt(4),
//         grid 1024 = 4 blocks/CU, wave-tile 32x32, f32 out + bias (R12) -------

__global__ __launch_bounds__(256, 4) void gemm_out64(
    const __hip_bfloat16* __restrict__ A,    // [M][K]  ctx
    const __hip_bfloat16* __restrict__ Bt,   // [N][K]  W_out^T
    const float* __restrict__ bias,          // [N]
    float* __restrict__ Cout,                // f32 [M][N]
    int M, int N, int K)
{
  __shared__ unsigned int lA[2][64 * 64 / 2];   // 2 x 8 KB
  __shared__ unsigned int lB[2][64 * 64 / 2];   // 2 x 8 KB
  const int tid = threadIdx.x;
  const int wave = tid >> 6, lane = tid & 63;
  const int m0 = blockIdx.y * 64, n0 = blockIdx.x * 64;
  const int wm = (wave >> 1) * 32, wn = (wave & 1) * 32;   // 2m x 2n waves, wave-tile 32x32
  const int l16 = lane >> 4, l15 = lane & 15;

  f32x4 acc[2][2];
  #pragma unroll
  for (int i = 0; i < 2; ++i)
    #pragma unroll
    for (int j = 0; j < 2; ++j) acc[i][j] = (f32x4){0.f, 0.f, 0.f, 0.f};

  auto stage = [&](int buf, int kt) {
    #pragma unroll
    for (int it = 0; it < 2; ++it) {
      const int c = it * 256 + tid;
      const int r = c >> 3, s8 = c & 7;
      const int ss = s8 ^ (r & 7);
      gload_lds16(A  + (size_t)(m0 + r) * K + kt * 64 + ss * 8, (char*)lA[buf] + c * 16);
      gload_lds16(Bt + (size_t)(n0 + r) * K + kt * 64 + ss * 8, (char*)lB[buf] + c * 16);
    }
  };

  const int nkt = K / 64;   // 16
  stage(0, 0);
  int cur = 0;
  for (int kt = 0; kt < nkt; ++kt) {
    const bool pf = (kt + 1 < nkt);
    if (pf) stage(cur ^ 1, kt + 1);
    if (pf) asm volatile("s_waitcnt vmcnt(4)" ::: "memory");
    else    asm volatile("s_waitcnt vmcnt(0)" ::: "memory");
    __builtin_amdgcn_s_barrier();
    __builtin_amdgcn_sched_barrier(0);
    #pragma unroll
    for (int ks = 0; ks < 2; ++ks) {
      short8 af[2], bfr[2];
      #pragma unroll
      for (int mi = 0; mi < 2; ++mi) {
        const int r = wm + mi * 16 + l15;
        const int slot = (ks * 4 + l16) ^ (r & 7);
        uint4 u = *(const uint4*)((const char*)lA[cur] + r * 128 + slot * 16);
        af[mi] = __builtin_bit_cast(short8, u);
      }
      #pragma unroll
      for (int ni = 0; ni < 2; ++ni) {
        const int r = wn + ni * 16 + l15;
        const int slot = (ks * 4 + l16) ^ (r & 7);
        uint4 u = *(const uint4*)((const char*)lB[cur] + r * 128 + slot * 16);
        bfr[ni] = __builtin_bit_cast(short8, u);
      }
      __builtin_amdgcn_s_setprio(1);
      #pragma unroll
      for (int mi = 0; mi < 2; ++mi)
        #pragma unroll
        for (int ni = 0; ni < 2; ++ni)
          acc[mi][ni] = __builtin_amdgcn_mfma_f32_16x16x32_bf16(af[mi], bfr[ni], acc[mi][ni], 0, 0, 0);
      __builtin_amdgcn_s_setprio(0);
    }
    __builtin_amdgcn_sched_barrier(0);
    __builtin_amdgcn_s_barrier();
    cur ^= 1;
  }

  #pragma unroll
  for (int ni = 0; ni < 2; ++ni) {
    const int cn = n0 + wn + ni * 16 + l15;
    const float bv = bias[cn];
    #pragma unroll
    for (int mi = 0; mi < 2; ++mi) {
      #pragma unroll
      for (int j = 0; j < 4; ++j) {
        const int rm = m0 + wm + mi * 16 + l16 * 4 + j;
        Cout[(size_t)rm * N + cn] = acc[mi][ni][j] + bv;
      }
    }
  }
}

// ---------------- sliding-window attention ----------------
// one block per (query-tile of 64, head); zero-padded K/V outside [0,S) matches reference.

__global__ __launch_bounds__(256) void attn_kernel(const __hip_bfloat16* __restrict__ qkv,
                                                   __hip_bfloat16* __restrict__ ctx){
  __shared__ unsigned int kbuf[KROWS * KPITCH_U];
  __shared__ unsigned int vbuf[KROWS * KPITCH_U];
  const int tid = threadIdx.x;
  const int h   = blockIdx.x & 15;
  const int qs0 = (blockIdx.x >> 4) * QT;

  // stage K/V window rows [qs0-16, qs0+79]
  #pragma unroll
  for (int it = 0; it < 3; ++it) {
    int c = tid + it * 256;            // 0..767
    int r = c >> 3, s8 = c & 7;
    int srow = qs0 - PAD + r;
    uint4 kv = make_uint4(0, 0, 0, 0), vv = make_uint4(0, 0, 0, 0);
    if ((unsigned)srow < (unsigned)S_LEN) {
      kv = ((const uint4*)(qkv + (size_t)srow * 3072 + h * 192 + 64))[s8];
      vv = ((const uint4*)(qkv + (size_t)srow * 3072 + h * 192 + 128))[s8];
    }
    *(uint4*)(kbuf + r * KPITCH_U + s8 * 4) = kv;
    *(uint4*)(vbuf + r * KPITCH_U + s8 * 4) = vv;
  }

  const int ql = tid >> 2, t4 = tid & 3;
  const uint4* qp = (const uint4*)(qkv + (size_t)(qs0 + ql) * 3072 + h * 192);
  float qf[64];
  #pragma unroll
  for (int c = 0; c < 8; ++c) {
    uint4 v = qp[c];
    qf[c*8+0] = bl(v.x); qf[c*8+1] = bh(v.x);
    qf[c*8+2] = bl(v.y); qf[c*8+3] = bh(v.y);
    qf[c*8+4] = bl(v.z); qf[c*8+5] = bh(v.z);
    qf[c*8+6] = bl(v.w); qf[c*8+7] = bh(v.w);
  }
  __syncthreads();

  float sc[9];
  #pragma unroll
  for (int j = 0; j < 9; ++j) sc[j] = 0.f;
  float mx = -1e30f;
  #pragma unroll
  for (int j = 0; j < 9; ++j) {
    int w = t4 + 4 * j;
    if (w < WIN) {
      int rw = ql + w;
      const uint4* kp = (const uint4*)(kbuf + rw * KPITCH_U);
      float d = 0.f;
      #pragma unroll
      for (int c = 0; c < 8; ++c) {
        uint4 kv = kp[c];
        d += qf[c*8+0]*bl(kv.x) + qf[c*8+1]*bh(kv.x)
           + qf[c*8+2]*bl(kv.y) + qf[c*8+3]*bh(kv.y)
           + qf[c*8+4]*bl(kv.z) + qf[c*8+5]*bh(kv.z)
           + qf[c*8+6]*bl(kv.w) + qf[c*8+7]*bh(kv.w);
      }
      sc[j] = d * 0.125f;
      mx = fmaxf(mx, sc[j]);
    }
  }
  mx = fmaxf(mx, __shfl_xor(mx, 1));
  mx = fmaxf(mx, __shfl_xor(mx, 2));
  float sum = 0.f;
  #pragma unroll
  for (int j = 0; j < 9; ++j) {
    int w = t4 + 4 * j;
    if (w < WIN) { sc[j] = __expf(sc[j] - mx); sum += sc[j]; }
  }
  sum += __shfl_xor(sum, 1);
  sum += __shfl_xor(sum, 2);
  const float inv = 1.0f / sum;
  #pragma unroll
  for (int j = 0; j < 9; ++j) sc[j] *= inv;

  float accd[16];
  #pragma unroll
  for (int i = 0; i < 16; ++i) accd[i] = 0.f;
  #pragma unroll
  for (int w = 0; w < WIN; ++w) {
    float wgt = __shfl(sc[w >> 2], ((tid & 63) & ~3) | (w & 3), 64);
    int rw = ql + w;
    const uint4* vp = (const uint4*)(vbuf + rw * KPITCH_U + t4 * 8);
    uint4 a = vp[0], b = vp[1];
    float vf[16];
    vf[0]=bl(a.x); vf[1]=bh(a.x); vf[2]=bl(a.y); vf[3]=bh(a.y);
    vf[4]=bl(a.z); vf[5]=bh(a.z); vf[6]=bl(a.w); vf[7]=bh(a.w);
    vf[8]=bl(b.x); vf[9]=bh(b.x); vf[10]=bl(b.y); vf[11]=bh(b.y);
    vf[12]=bl(b.z); vf[13]=bh(b.z); vf[14]=bl(b.w); vf[15]=bh(b.w);
    #pragma unroll
    for (int i = 0; i < 16; ++i) accd[i] += wgt * vf[i];
  }

  unsigned short* op = (unsigned short*)ctx + (size_t)(qs0 + ql) * 1024 + h * 64 + t4 * 16;
  uint4 o1, o2;
  o1.x = pack2(accd[0], accd[1]);  o1.y = pack2(accd[2], accd[3]);
  o1.z = pack2(accd[4], accd[5]);  o1.w = pack2(accd[6], accd[7]);
  o2.x = pack2(accd[8], accd[9]);  o2.y = pack2(accd[10], accd[11]);
  o2.z = pack2(accd[12], accd[13]); o2.w = pack2(accd[14], accd[15]);
  *(uint4*)op = o1;
  *((uint4*)op + 1) = o2;
}

// ---------------- launch ----------------

extern "C" void kernel_launch(void* const* d_in, const int* in_sizes, int n_in,
                              void* d_out, int out_size, void* d_ws, size_t ws_size,
                              hipStream_t stream)
{
  const float* x     = (const float*)d_in[0];
  const float* rot   = (const float*)d_in[1];
  const float* W_qkv = (const float*)d_in[2];
  const float* b_qkv = (const float*)d_in[3];
  const float* W_out = (const float*)d_in[4];
  const float* b_out = (const float*)d_in[5];
  float* out = (float*)d_out;

  char* ws = (char*)d_ws;
  __hip_bfloat16* xb   = (__hip_bfloat16*)(ws + 0);          //  8 MB
  __hip_bfloat16* Wt1  = (__hip_bfloat16*)(ws + 8388608);    //  6 MB  [3072][1024]
  __hip_bfloat16* Wt2  = (__hip_bfloat16*)(ws + 14680064);   //  2 MB  [1024][1024]
  __hip_bfloat16* qkvb = (__hip_bfloat16*)(ws + 16777216);   // 24 MB  [4096][3072]
  __hip_bfloat16* ctx  = (__hip_bfloat16*)(ws + 41943040);   //  8 MB  [4096][1024]
  float2* csq          = (float2*)(ws + 50331648);           //  1 MB  [4096][32] (cos,sin)

  prep_all<<<6656, 256, 0, stream>>>(rot, csq, x, xb, W_qkv, Wt1, W_out, Wt2);
  gemm_qkv_rope<<<dim3(3072 / 256, 4096 / 256), 512, 0, stream>>>(xb, Wt1, b_qkv, csq,
                                                                  (unsigned short*)qkvb, 4096, 3072, 1024);
  attn_kernel<<<64 * 16, 256, 0, stream>>>(qkvb, ctx);
  gemm_out64<<<dim3(1024 / 64, 4096 / 64), 256, 0, stream>>>(ctx, Wt2, b_out, out, 4096, 1024, 1024);
}

// Round 14
// 90.192 us; speedup vs baseline: 1.0378x; 1.0378x over previous
//
#include <hip/hip_runtime.h>
#include <hip/hip_bf16.h>

#define S_LEN 4096
#define NH 16
#define HD 64
#define WIN 33
#define PAD 16
#define QT 64
#define KROWS 96
#define KPITCH_U 36   // uints per LDS row (72 shorts = 144B, breaks bank conflicts)

typedef short short8 __attribute__((ext_vector_type(8)));
typedef float f32x4 __attribute__((ext_vector_type(4)));

__device__ __forceinline__ float bl(unsigned u){ return __uint_as_float(u << 16); }
__device__ __forceinline__ float bh(unsigned u){ return __uint_as_float(u & 0xffff0000u); }
__device__ __forceinline__ unsigned f2bfu(float f){
  unsigned u = __float_as_uint(f);
  return (u + 0x7fffu + ((u >> 16) & 1u)) >> 16;   // RNE
}
__device__ __forceinline__ unsigned pack2(float a, float b){ return f2bfu(a) | (f2bfu(b) << 16); }

__device__ __forceinline__ void gload_lds16(const void* g, void* l){
  __builtin_amdgcn_global_load_lds(
      (const __attribute__((address_space(1))) void*)g,
      (__attribute__((address_space(3))) void*)l, 16, 0, 0);
}

// ---------------- fused prep kernel ----------------
// b in [0,512): rope float2 table; [512,2560): x->bf16; [2560,5632): W_qkv^T; [5632,6656): W_out^T

__global__ __launch_bounds__(256) void prep_all(
    const float* __restrict__ rot, float2* __restrict__ csq,
    const float* __restrict__ x, __hip_bfloat16* __restrict__ xb,
    const float* __restrict__ Wq, __hip_bfloat16* __restrict__ Wt1,
    const float* __restrict__ Wo, __hip_bfloat16* __restrict__ Wt2)
{
  __shared__ float tile[32][33];
  const int b = blockIdx.x, tid = threadIdx.x;
  if (b < 512) {
    int t = b * 256 + tid;                 // 131072 = 4096*32 exactly
    float v = rot[t], sv, cv;
    __sincosf(v, &sv, &cv);
    csq[t] = make_float2(cv, sv);
  } else if (b < 2560) {
    int t = (b - 512) * 256 + tid;         // one thread = 8 elements
    const float4* p = (const float4*)x + (size_t)t * 2;
    float4 a = p[0], c = p[1];
    uint4 o;
    o.x = pack2(a.x, a.y); o.y = pack2(a.z, a.w);
    o.z = pack2(c.x, c.y); o.w = pack2(c.z, c.w);
    ((uint4*)xb)[t] = o;
  } else {
    const float* in; unsigned short* out; int R, C, bx, by;
    if (b < 5632) { int bb = b - 2560; in = Wq; out = (unsigned short*)Wt1; R = 1024; C = 3072; bx = bb % 96; by = bb / 96; }
    else          { int bb = b - 5632; in = Wo; out = (unsigned short*)Wt2; R = 1024; C = 1024; bx = bb % 32; by = bb / 32; }
    int c0 = bx * 32, r0 = by * 32;
    int tx = tid & 31, ty = tid >> 5;
    #pragma unroll
    for (int i = 0; i < 4; ++i) {
      int r = ty + i * 8;
      tile[r][tx] = in[(size_t)(r0 + r) * C + c0 + tx];
    }
    __syncthreads();
    #pragma unroll
    for (int i = 0; i < 4; ++i) {
      int cc = ty + i * 8;
      out[(size_t)(c0 + cc) * R + r0 + tx] = (unsigned short)f2bfu(tile[tx][cc]);
    }
  }
}

// ------- GEMM1: 256x192 tile, 512 thr / 8 waves (wave-tile 128x48 -> 34% LDS ceiling),
//         BK=64, 112 KB dbuf, grid 256 = exactly 1 block/CU (no idle CUs),
//         minimal sync: 2 barriers + counted vmcnt(7) per K-tile, no sched_barrier,
//         compiler-scheduled tile body, bias+RoPE epilogue -------

__global__ __launch_bounds__(512) void gemm_qkv_rope(
    const __hip_bfloat16* __restrict__ A,    // [M][K]  x (bf16)
    const __hip_bfloat16* __restrict__ Bt,   // [N][K]  W_qkv^T (bf16)
    const float* __restrict__ bias,          // [N]
    const float2* __restrict__ csq,          // [S][32] (cos,sin)
    unsigned short* __restrict__ Cout,       // bf16 [M][N]
    int M, int N, int K)
{
  __shared__ short lA[2][256][64];           // 64 KB
  __shared__ short lB[2][192][64];           // 48 KB
  const int tid = threadIdx.x;
  const int wave = tid >> 6, lane = tid & 63;
  const int m0 = blockIdx.y * 256, n0 = blockIdx.x * 192;
  const int wm = (wave >> 2) * 128, wn = (wave & 3) * 48;   // 2m x 4n waves
  const int l16 = lane >> 4, l15 = lane & 15;

  f32x4 acc[8][3];
  #pragma unroll
  for (int i = 0; i < 8; ++i)
    #pragma unroll
    for (int j = 0; j < 3; ++j) acc[i][j] = (f32x4){0.f, 0.f, 0.f, 0.f};

  // stage tile kt into buf: A 2048 chunks (4/thr) + B 1536 chunks (3/thr) = 7 loads/thread.
  // linear LDS dest, inverse-swizzled global source (rule #21).
  auto stage = [&](int buf, int kt) {
    #pragma unroll
    for (int it = 0; it < 4; ++it) {
      const int c = it * 512 + tid;
      const int r = c >> 3, s8 = c & 7;
      const int ss = s8 ^ (r & 7);
      gload_lds16(A + (size_t)(m0 + r) * K + kt * 64 + ss * 8,
                  (char*)&lA[buf][0][0] + c * 16);
    }
    #pragma unroll
    for (int it = 0; it < 3; ++it) {
      const int c = it * 512 + tid;
      const int r = c >> 3, s8 = c & 7;
      const int ss = s8 ^ (r & 7);
      gload_lds16(Bt + (size_t)(n0 + r) * K + kt * 64 + ss * 8,
                  (char*)&lB[buf][0][0] + c * 16);
    }
  };

  const int nkt = K / 64;   // 16
  stage(0, 0);
  for (int kt = 0; kt < nkt; ++kt) {
    const int cur = kt & 1;
    __builtin_amdgcn_s_barrier();            // all waves done reading buf^1 (tile kt-1)
    if (kt + 1 < nkt) stage(cur ^ 1, kt + 1);   // fill the now-dead buffer, 7 loads in flight
    // counted wait: tile kt's 7 loads (issued a full tile ago) retired; kt+1's 7 stay in flight
    if (kt + 1 < nkt) asm volatile("s_waitcnt vmcnt(7)" ::: "memory");
    else              asm volatile("s_waitcnt vmcnt(0)" ::: "memory");
    __builtin_amdgcn_s_barrier();            // everyone's tile-kt loads landed
    // whole-tile body: 16 A-reads + 6 B-reads + 48 MFMA, compiler-scheduled (no sched_barrier)
    #pragma unroll
    for (int ks = 0; ks < 2; ++ks) {
      short8 af[8], bf[3];
      #pragma unroll
      for (int mi = 0; mi < 8; ++mi) {
        const int r = wm + mi * 16 + l15;
        const int slot = (ks * 4 + l16) ^ (r & 7);
        af[mi] = *(const short8*)&lA[cur][r][slot * 8];
      }
      #pragma unroll
      for (int ni = 0; ni < 3; ++ni) {
        const int r = wn + ni * 16 + l15;
        const int slot = (ks * 4 + l16) ^ (r & 7);
        bf[ni] = *(const short8*)&lB[cur][r][slot * 8];
      }
      #pragma unroll
      for (int mi = 0; mi < 8; ++mi)
        #pragma unroll
        for (int ni = 0; ni < 3; ++ni)
          acc[mi][ni] = __builtin_amdgcn_mfma_f32_16x16x32_bf16(af[mi], bf[ni], acc[mi][ni], 0, 0, 0);
    }
  }

  // epilogue: C/D layout col=lane&15, row=(lane>>4)*4+reg.
  // n0 is a multiple of 192 (head-aligned): rseg = wn + bj*16 + l15 within [0,192):
  // q [0,64) k [64,128) v [128,192); RoPE pair via shfl_xor(1).
  #pragma unroll
  for (int bj = 0; bj < 3; ++bj) {
    const int cn = n0 + wn + bj * 16 + l15;
    const int rseg = wn + bj * 16 + l15;     // wave-uniform branch per bj (16-groups don't straddle)
    const float bv = bias[cn];
    if (rseg < 128) {                        // q or k -> RoPE
      const int i = (rseg & 63) >> 1;
      const float sgn = (cn & 1) ? 1.f : -1.f;
      #pragma unroll
      for (int ai = 0; ai < 8; ++ai) {
        #pragma unroll
        for (int j = 0; j < 4; ++j) {
          const int rm = m0 + wm + ai * 16 + l16 * 4 + j;
          const float v = acc[ai][bj][j] + bv;
          const float p = __shfl_xor(v, 1);
          const float2 cs = csq[rm * 32 + i];
          Cout[(size_t)rm * N + cn] = (unsigned short)f2bfu(v * cs.x + p * (sgn * cs.y));
        }
      }
    } else {
      #pragma unroll
      for (int ai = 0; ai < 8; ++ai) {
        #pragma unroll
        for (int j = 0; j < 4; ++j) {
          const int rm = m0 + wm + ai * 16 + l16 * 4 + j;
          Cout[(size_t)rm * N + cn] = (unsigned short)f2bfu(acc[ai][bj][j] + bv);
        }
      }
    }
  }
}

// ------- GEMM2: 64x64 tile, BK=64, double-buffered 32 KB LDS, counted vmcnt(4),
//         grid 1024 = 4 blocks/CU, wave-tile 32x32, f32 out + bias (R12) -------

__global__ __launch_bounds__(256, 4) void gemm_out64(
    const __hip_bfloat16* __restrict__ A,    // [M][K]  ctx
    const __hip_bfloat16* __restrict__ Bt,   // [N][K]  W_out^T
    const float* __restrict__ bias,          // [N]
    float* __restrict__ Cout,                // f32 [M][N]
    int M, int N, int K)
{
  __shared__ unsigned int lA[2][64 * 64 / 2];   // 2 x 8 KB
  __shared__ unsigned int lB[2][64 * 64 / 2];   // 2 x 8 KB
  const int tid = threadIdx.x;
  const int wave = tid >> 6, lane = tid & 63;
  const int m0 = blockIdx.y * 64, n0 = blockIdx.x * 64;
  const int wm = (wave >> 1) * 32, wn = (wave & 1) * 32;   // 2m x 2n waves, wave-tile 32x32
  const int l16 = lane >> 4, l15 = lane & 15;

  f32x4 acc[2][2];
  #pragma unroll
  for (int i = 0; i < 2; ++i)
    #pragma unroll
    for (int j = 0; j < 2; ++j) acc[i][j] = (f32x4){0.f, 0.f, 0.f, 0.f};

  auto stage = [&](int buf, int kt) {
    #pragma unroll
    for (int it = 0; it < 2; ++it) {
      const int c = it * 256 + tid;
      const int r = c >> 3, s8 = c & 7;
      const int ss = s8 ^ (r & 7);
      gload_lds16(A  + (size_t)(m0 + r) * K + kt * 64 + ss * 8, (char*)lA[buf] + c * 16);
      gload_lds16(Bt + (size_t)(n0 + r) * K + kt * 64 + ss * 8, (char*)lB[buf] + c * 16);
    }
  };

  const int nkt = K / 64;   // 16
  stage(0, 0);
  int cur = 0;
  for (int kt = 0; kt < nkt; ++kt) {
    const bool pf = (kt + 1 < nkt);
    if (pf) stage(cur ^ 1, kt + 1);
    if (pf) asm volatile("s_waitcnt vmcnt(4)" ::: "memory");
    else    asm volatile("s_waitcnt vmcnt(0)" ::: "memory");
    __builtin_amdgcn_s_barrier();
    __builtin_amdgcn_sched_barrier(0);
    #pragma unroll
    for (int ks = 0; ks < 2; ++ks) {
      short8 af[2], bfr[2];
      #pragma unroll
      for (int mi = 0; mi < 2; ++mi) {
        const int r = wm + mi * 16 + l15;
        const int slot = (ks * 4 + l16) ^ (r & 7);
        uint4 u = *(const uint4*)((const char*)lA[cur] + r * 128 + slot * 16);
        af[mi] = __builtin_bit_cast(short8, u);
      }
      #pragma unroll
      for (int ni = 0; ni < 2; ++ni) {
        const int r = wn + ni * 16 + l15;
        const int slot = (ks * 4 + l16) ^ (r & 7);
        uint4 u = *(const uint4*)((const char*)lB[cur] + r * 128 + slot * 16);
        bfr[ni] = __builtin_bit_cast(short8, u);
      }
      __builtin_amdgcn_s_setprio(1);
      #pragma unroll
      for (int mi = 0; mi < 2; ++mi)
        #pragma unroll
        for (int ni = 0; ni < 2; ++ni)
          acc[mi][ni] = __builtin_amdgcn_mfma_f32_16x16x32_bf16(af[mi], bfr[ni], acc[mi][ni], 0, 0, 0);
      __builtin_amdgcn_s_setprio(0);
    }
    __builtin_amdgcn_sched_barrier(0);
    __builtin_amdgcn_s_barrier();
    cur ^= 1;
  }

  #pragma unroll
  for (int ni = 0; ni < 2; ++ni) {
    const int cn = n0 + wn + ni * 16 + l15;
    const float bv = bias[cn];
    #pragma unroll
    for (int mi = 0; mi < 2; ++mi) {
      #pragma unroll
      for (int j = 0; j < 4; ++j) {
        const int rm = m0 + wm + mi * 16 + l16 * 4 + j;
        Cout[(size_t)rm * N + cn] = acc[mi][ni][j] + bv;
      }
    }
  }
}

// ---------------- sliding-window attention ----------------
// one block per (query-tile of 64, head); zero-padded K/V outside [0,S) matches reference.

__global__ __launch_bounds__(256) void attn_kernel(const __hip_bfloat16* __restrict__ qkv,
                                                   __hip_bfloat16* __restrict__ ctx){
  __shared__ unsigned int kbuf[KROWS * KPITCH_U];
  __shared__ unsigned int vbuf[KROWS * KPITCH_U];
  const int tid = threadIdx.x;
  const int h   = blockIdx.x & 15;
  const int qs0 = (blockIdx.x >> 4) * QT;

  // stage K/V window rows [qs0-16, qs0+79]
  #pragma unroll
  for (int it = 0; it < 3; ++it) {
    int c = tid + it * 256;            // 0..767
    int r = c >> 3, s8 = c & 7;
    int srow = qs0 - PAD + r;
    uint4 kv = make_uint4(0, 0, 0, 0), vv = make_uint4(0, 0, 0, 0);
    if ((unsigned)srow < (unsigned)S_LEN) {
      kv = ((const uint4*)(qkv + (size_t)srow * 3072 + h * 192 + 64))[s8];
      vv = ((const uint4*)(qkv + (size_t)srow * 3072 + h * 192 + 128))[s8];
    }
    *(uint4*)(kbuf + r * KPITCH_U + s8 * 4) = kv;
    *(uint4*)(vbuf + r * KPITCH_U + s8 * 4) = vv;
  }

  const int ql = tid >> 2, t4 = tid & 3;
  const uint4* qp = (const uint4*)(qkv + (size_t)(qs0 + ql) * 3072 + h * 192);
  float qf[64];
  #pragma unroll
  for (int c = 0; c < 8; ++c) {
    uint4 v = qp[c];
    qf[c*8+0] = bl(v.x); qf[c*8+1] = bh(v.x);
    qf[c*8+2] = bl(v.y); qf[c*8+3] = bh(v.y);
    qf[c*8+4] = bl(v.z); qf[c*8+5] = bh(v.z);
    qf[c*8+6] = bl(v.w); qf[c*8+7] = bh(v.w);
  }
  __syncthreads();

  float sc[9];
  #pragma unroll
  for (int j = 0; j < 9; ++j) sc[j] = 0.f;
  float mx = -1e30f;
  #pragma unroll
  for (int j = 0; j < 9; ++j) {
    int w = t4 + 4 * j;
    if (w < WIN) {
      int rw = ql + w;
      const uint4* kp = (const uint4*)(kbuf + rw * KPITCH_U);
      float d = 0.f;
      #pragma unroll
      for (int c = 0; c < 8; ++c) {
        uint4 kv = kp[c];
        d += qf[c*8+0]*bl(kv.x) + qf[c*8+1]*bh(kv.x)
           + qf[c*8+2]*bl(kv.y) + qf[c*8+3]*bh(kv.y)
           + qf[c*8+4]*bl(kv.z) + qf[c*8+5]*bh(kv.z)
           + qf[c*8+6]*bl(kv.w) + qf[c*8+7]*bh(kv.w);
      }
      sc[j] = d * 0.125f;
      mx = fmaxf(mx, sc[j]);
    }
  }
  mx = fmaxf(mx, __shfl_xor(mx, 1));
  mx = fmaxf(mx, __shfl_xor(mx, 2));
  float sum = 0.f;
  #pragma unroll
  for (int j = 0; j < 9; ++j) {
    int w = t4 + 4 * j;
    if (w < WIN) { sc[j] = __expf(sc[j] - mx); sum += sc[j]; }
  }
  sum += __shfl_xor(sum, 1);
  sum += __shfl_xor(sum, 2);
  const float inv = 1.0f / sum;
  #pragma unroll
  for (int j = 0; j < 9; ++j) sc[j] *= inv;

  float accd[16];
  #pragma unroll
  for (int i = 0; i < 16; ++i) accd[i] = 0.f;
  #pragma unroll
  for (int w = 0; w < WIN; ++w) {
    float wgt = __shfl(sc[w >> 2], ((tid & 63) & ~3) | (w & 3), 64);
    int rw = ql + w;
    const uint4* vp = (const uint4*)(vbuf + rw * KPITCH_U + t4 * 8);
    uint4 a = vp[0], b = vp[1];
    float vf[16];
    vf[0]=bl(a.x); vf[1]=bh(a.x); vf[2]=bl(a.y); vf[3]=bh(a.y);
    vf[4]=bl(a.z); vf[5]=bh(a.z); vf[6]=bl(a.w); vf[7]=bh(a.w);
    vf[8]=bl(b.x); vf[9]=bh(b.x); vf[10]=bl(b.y); vf[11]=bh(b.y);
    vf[12]=bl(b.z); vf[13]=bh(b.z); vf[14]=bl(b.w); vf[15]=bh(b.w);
    #pragma unroll
    for (int i = 0; i < 16; ++i) accd[i] += wgt * vf[i];
  }

  unsigned short* op = (unsigned short*)ctx + (size_t)(qs0 + ql) * 1024 + h * 64 + t4 * 16;
  uint4 o1, o2;
  o1.x = pack2(accd[0], accd[1]);  o1.y = pack2(accd[2], accd[3]);
  o1.z = pack2(accd[4], accd[5]);  o1.w = pack2(accd[6], accd[7]);
  o2.x = pack2(accd[8], accd[9]);  o2.y = pack2(accd[10], accd[11]);
  o2.z = pack2(accd[12], accd[13]); o2.w = pack2(accd[14], accd[15]);
  *(uint4*)op = o1;
  *((uint4*)op + 1) = o2;
}

// ---------------- launch ----------------

extern "C" void kernel_launch(void* const* d_in, const int* in_sizes, int n_in,
                              void* d_out, int out_size, void* d_ws, size_t ws_size,
                              hipStream_t stream)
{
  const float* x     = (const float*)d_in[0];
  const float* rot   = (const float*)d_in[1];
  const float* W_qkv = (const float*)d_in[2];
  const float* b_qkv = (const float*)d_in[3];
  const float* W_out = (const float*)d_in[4];
  const float* b_out = (const float*)d_in[5];
  float* out = (float*)d_out;

  char* ws = (char*)d_ws;
  __hip_bfloat16* xb   = (__hip_bfloat16*)(ws + 0);          //  8 MB
  __hip_bfloat16* Wt1  = (__hip_bfloat16*)(ws + 8388608);    //  6 MB  [3072][1024]
  __hip_bfloat16* Wt2  = (__hip_bfloat16*)(ws + 14680064);   //  2 MB  [1024][1024]
  __hip_bfloat16* qkvb = (__hip_bfloat16*)(ws + 16777216);   // 24 MB  [4096][3072]
  __hip_bfloat16* ctx  = (__hip_bfloat16*)(ws + 41943040);   //  8 MB  [4096][1024]
  float2* csq          = (float2*)(ws + 50331648);           //  1 MB  [4096][32] (cos,sin)

  prep_all<<<6656, 256, 0, stream>>>(rot, csq, x, xb, W_qkv, Wt1, W_out, Wt2);
  gemm_qkv_rope<<<dim3(3072 / 192, 4096 / 256), 512, 0, stream>>>(xb, Wt1, b_qkv, csq,
                                                                  (unsigned short*)qkvb, 4096, 3072, 1024);
  attn_kernel<<<64 * 16, 256, 0, stream>>>(qkvb, ctx);
  gemm_out64<<<dim3(1024 / 64, 4096 / 64), 256, 0, stream>>>(ctx, Wt2, b_out, out, 4096, 1024, 1024);
}

// Round 15
// 86.565 us; speedup vs baseline: 1.0813x; 1.0419x over previous
//
#include <hip/hip_runtime.h>
#include <hip/hip_bf16.h>

#define S_LEN 4096
#define NH 16
#define HD 64
#define WIN 33
#define PAD 16
#define QT 64
#define KROWS 96
#define KPITCH_U 36   // uints per LDS row (72 shorts = 144B, breaks bank conflicts)

typedef short short8 __attribute__((ext_vector_type(8)));
typedef float f32x4 __attribute__((ext_vector_type(4)));

__device__ __forceinline__ float bl(unsigned u){ return __uint_as_float(u << 16); }
__device__ __forceinline__ float bh(unsigned u){ return __uint_as_float(u & 0xffff0000u); }
__device__ __forceinline__ unsigned f2bfu(float f){
  unsigned u = __float_as_uint(f);
  return (u + 0x7fffu + ((u >> 16) & 1u)) >> 16;   // RNE
}
__device__ __forceinline__ unsigned pack2(float a, float b){ return f2bfu(a) | (f2bfu(b) << 16); }

__device__ __forceinline__ void gload_lds16(const void* g, void* l){
  __builtin_amdgcn_global_load_lds(
      (const __attribute__((address_space(1))) void*)g,
      (__attribute__((address_space(3))) void*)l, 16, 0, 0);
}

// ---------------- fused prep kernel ----------------
// b in [0,512): rope float2 table; [512,2560): x->bf16; [2560,5632): W_qkv^T; [5632,6656): W_out^T

__global__ __launch_bounds__(256) void prep_all(
    const float* __restrict__ rot, float2* __restrict__ csq,
    const float* __restrict__ x, __hip_bfloat16* __restrict__ xb,
    const float* __restrict__ Wq, __hip_bfloat16* __restrict__ Wt1,
    const float* __restrict__ Wo, __hip_bfloat16* __restrict__ Wt2)
{
  __shared__ float tile[32][33];
  const int b = blockIdx.x, tid = threadIdx.x;
  if (b < 512) {
    int t = b * 256 + tid;                 // 131072 = 4096*32 exactly
    float v = rot[t], sv, cv;
    __sincosf(v, &sv, &cv);
    csq[t] = make_float2(cv, sv);
  } else if (b < 2560) {
    int t = (b - 512) * 256 + tid;         // one thread = 8 elements
    const float4* p = (const float4*)x + (size_t)t * 2;
    float4 a = p[0], c = p[1];
    uint4 o;
    o.x = pack2(a.x, a.y); o.y = pack2(a.z, a.w);
    o.z = pack2(c.x, c.y); o.w = pack2(c.z, c.w);
    ((uint4*)xb)[t] = o;
  } else {
    const float* in; unsigned short* out; int R, C, bx, by;
    if (b < 5632) { int bb = b - 2560; in = Wq; out = (unsigned short*)Wt1; R = 1024; C = 3072; bx = bb % 96; by = bb / 96; }
    else          { int bb = b - 5632; in = Wo; out = (unsigned short*)Wt2; R = 1024; C = 1024; bx = bb % 32; by = bb / 32; }
    int c0 = bx * 32, r0 = by * 32;
    int tx = tid & 31, ty = tid >> 5;
    #pragma unroll
    for (int i = 0; i < 4; ++i) {
      int r = ty + i * 8;
      tile[r][tx] = in[(size_t)(r0 + r) * C + c0 + tx];
    }
    __syncthreads();
    #pragma unroll
    for (int i = 0; i < 4; ++i) {
      int cc = ty + i * 8;
      out[(size_t)(c0 + cc) * R + r0 + tx] = (unsigned short)f2bfu(tile[tx][cc]);
    }
  }
}

// ------- GEMM1: 128x96 tile, BK=64, SINGLE-buffered LDS (28 KB -> 4 blocks/CU resident),
//         m97-style 2-barrier loop, bias+RoPE epilogue, bf16 out (R6-proven, reverted) -------

__global__ __launch_bounds__(256, 4) void gemm_qkv_rope(
    const __hip_bfloat16* __restrict__ A,    // [M][K]  x (bf16)
    const __hip_bfloat16* __restrict__ Bt,   // [N][K]  W_qkv^T (bf16)
    const float* __restrict__ bias,          // [N]
    const float2* __restrict__ csq,          // [S][32] (cos,sin)
    unsigned short* __restrict__ Cout,       // bf16 [M][N]
    int M, int N, int K)
{
  __shared__ unsigned int lA[128 * 64 / 2];   // 16 KB
  __shared__ unsigned int lB[96 * 64 / 2];    // 12 KB
  const int tid = threadIdx.x;
  const int wave = tid >> 6, lane = tid & 63;
  const int m0 = blockIdx.y * 128, n0 = blockIdx.x * 96;
  const int wm = (wave >> 1) * 64, wn = (wave & 1) * 48;   // 2m x 2n waves, wave-tile 64x48
  const int l16 = lane >> 4, l15 = lane & 15;

  f32x4 acc[4][3];
  #pragma unroll
  for (int i = 0; i < 4; ++i)
    #pragma unroll
    for (int j = 0; j < 3; ++j) acc[i][j] = (f32x4){0.f, 0.f, 0.f, 0.f};

  const int nkt = K / 64;   // 16
  for (int kt = 0; kt < nkt; ++kt) {
    __syncthreads();        // prior reads of LDS done before overwrite
    // stage: linear LDS dest, inverse-swizzled global source (rule #21)
    #pragma unroll
    for (int it = 0; it < 4; ++it) {        // A: 128 rows x 8 slots = 1024 chunks
      const int c = it * 256 + tid;
      const int r = c >> 3, s8 = c & 7;
      const int ss = s8 ^ (r & 7);
      gload_lds16(A + (size_t)(m0 + r) * K + kt * 64 + ss * 8, (char*)lA + c * 16);
    }
    #pragma unroll
    for (int it = 0; it < 3; ++it) {        // B: 96 rows x 8 slots = 768 chunks
      const int c = it * 256 + tid;
      const int r = c >> 3, s8 = c & 7;
      const int ss = s8 ^ (r & 7);
      gload_lds16(Bt + (size_t)(n0 + r) * K + kt * 64 + ss * 8, (char*)lB + c * 16);
    }
    __syncthreads();        // drains vmcnt(0): tile ready
    #pragma unroll
    for (int ks = 0; ks < 2; ++ks) {
      short8 af[4], bfr[3];
      #pragma unroll
      for (int mi = 0; mi < 4; ++mi) {
        const int r = wm + mi * 16 + l15;
        const int slot = (ks * 4 + l16) ^ (r & 7);
        uint4 u = *(const uint4*)((const char*)lA + r * 128 + slot * 16);
        af[mi] = __builtin_bit_cast(short8, u);
      }
      #pragma unroll
      for (int ni = 0; ni < 3; ++ni) {
        const int r = wn + ni * 16 + l15;
        const int slot = (ks * 4 + l16) ^ (r & 7);
        uint4 u = *(const uint4*)((const char*)lB + r * 128 + slot * 16);
        bfr[ni] = __builtin_bit_cast(short8, u);
      }
      #pragma unroll
      for (int mi = 0; mi < 4; ++mi)
        #pragma unroll
        for (int ni = 0; ni < 3; ++ni)
          acc[mi][ni] = __builtin_amdgcn_mfma_f32_16x16x32_bf16(af[mi], bfr[ni], acc[mi][ni], 0, 0, 0);
    }
  }

  // epilogue: C/D layout col=lane&15, row=(lane>>4)*4+reg.
  // cols: rseg = cn%192: q [0,64) k [64,128) v [128,192); RoPE pair via shfl_xor(1).
  #pragma unroll
  for (int ni = 0; ni < 3; ++ni) {
    const int cn = n0 + wn + ni * 16 + l15;
    const int rseg = cn % 192;               // wave-uniform per ni (16-col groups don't straddle)
    const float bv = bias[cn];
    if (rseg < 128) {                        // q or k -> RoPE
      const int i = (rseg & 63) >> 1;
      const float sgn = (cn & 1) ? 1.f : -1.f;
      #pragma unroll
      for (int mi = 0; mi < 4; ++mi) {
        #pragma unroll
        for (int j = 0; j < 4; ++j) {
          const int rm = m0 + wm + mi * 16 + l16 * 4 + j;
          const float v = acc[mi][ni][j] + bv;
          const float p = __shfl_xor(v, 1);
          const float2 cs = csq[rm * 32 + i];
          Cout[(size_t)rm * N + cn] = (unsigned short)f2bfu(v * cs.x + p * (sgn * cs.y));
        }
      }
    } else {
      #pragma unroll
      for (int mi = 0; mi < 4; ++mi) {
        #pragma unroll
        for (int j = 0; j < 4; ++j) {
          const int rm = m0 + wm + mi * 16 + l16 * 4 + j;
          Cout[(size_t)rm * N + cn] = (unsigned short)f2bfu(acc[mi][ni][j] + bv);
        }
      }
    }
  }
}

// ------- GEMM2: 64x64 tile, BK=64, dbuf + counted vmcnt(4), grid 1024 = 4 blocks/CU,
//         XCD-clustered block swizzle: each XCD owns an 8-m-row slice x all n ->
//         per-XCD working set 1MB A-slice + 2MB B < 4MB L2 (T1 mechanism) -------

__global__ __launch_bounds__(256, 4) void gemm_out64(
    const __hip_bfloat16* __restrict__ A,    // [M][K]  ctx
    const __hip_bfloat16* __restrict__ Bt,   // [N][K]  W_out^T
    const float* __restrict__ bias,          // [N]
    float* __restrict__ Cout,                // f32 [M][N]
    int M, int N, int K)
{
  __shared__ unsigned int lA[2][64 * 64 / 2];   // 2 x 8 KB
  __shared__ unsigned int lB[2][64 * 64 / 2];   // 2 x 8 KB
  const int tid = threadIdx.x;
  const int wave = tid >> 6, lane = tid & 63;
  // XCD swizzle: HW round-robins linear block id across 8 XCDs (id%8 = XCD).
  // swz = (flat&7)*128 + (flat>>3) is bijective on 1024 and gives XCD x the
  // contiguous swz range [x*128,(x+1)*128) = m-rows [x*8,(x+1)*8) x all 16 n.
  const int flat = blockIdx.y * 16 + blockIdx.x;
  const int swz = (flat & 7) * 128 + (flat >> 3);
  const int m0 = (swz >> 4) * 64, n0 = (swz & 15) * 64;
  const int wm = (wave >> 1) * 32, wn = (wave & 1) * 32;   // 2m x 2n waves, wave-tile 32x32
  const int l16 = lane >> 4, l15 = lane & 15;

  f32x4 acc[2][2];
  #pragma unroll
  for (int i = 0; i < 2; ++i)
    #pragma unroll
    for (int j = 0; j < 2; ++j) acc[i][j] = (f32x4){0.f, 0.f, 0.f, 0.f};

  auto stage = [&](int buf, int kt) {
    #pragma unroll
    for (int it = 0; it < 2; ++it) {
      const int c = it * 256 + tid;
      const int r = c >> 3, s8 = c & 7;
      const int ss = s8 ^ (r & 7);
      gload_lds16(A  + (size_t)(m0 + r) * K + kt * 64 + ss * 8, (char*)lA[buf] + c * 16);
      gload_lds16(Bt + (size_t)(n0 + r) * K + kt * 64 + ss * 8, (char*)lB[buf] + c * 16);
    }
  };

  const int nkt = K / 64;   // 16
  stage(0, 0);
  int cur = 0;
  for (int kt = 0; kt < nkt; ++kt) {
    const bool pf = (kt + 1 < nkt);
    if (pf) stage(cur ^ 1, kt + 1);
    if (pf) asm volatile("s_waitcnt vmcnt(4)" ::: "memory");
    else    asm volatile("s_waitcnt vmcnt(0)" ::: "memory");
    __builtin_amdgcn_s_barrier();
    __builtin_amdgcn_sched_barrier(0);
    #pragma unroll
    for (int ks = 0; ks < 2; ++ks) {
      short8 af[2], bfr[2];
      #pragma unroll
      for (int mi = 0; mi < 2; ++mi) {
        const int r = wm + mi * 16 + l15;
        const int slot = (ks * 4 + l16) ^ (r & 7);
        uint4 u = *(const uint4*)((const char*)lA[cur] + r * 128 + slot * 16);
        af[mi] = __builtin_bit_cast(short8, u);
      }
      #pragma unroll
      for (int ni = 0; ni < 2; ++ni) {
        const int r = wn + ni * 16 + l15;
        const int slot = (ks * 4 + l16) ^ (r & 7);
        uint4 u = *(const uint4*)((const char*)lB[cur] + r * 128 + slot * 16);
        bfr[ni] = __builtin_bit_cast(short8, u);
      }
      __builtin_amdgcn_s_setprio(1);
      #pragma unroll
      for (int mi = 0; mi < 2; ++mi)
        #pragma unroll
        for (int ni = 0; ni < 2; ++ni)
          acc[mi][ni] = __builtin_amdgcn_mfma_f32_16x16x32_bf16(af[mi], bfr[ni], acc[mi][ni], 0, 0, 0);
      __builtin_amdgcn_s_setprio(0);
    }
    __builtin_amdgcn_sched_barrier(0);
    __builtin_amdgcn_s_barrier();
    cur ^= 1;
  }

  #pragma unroll
  for (int ni = 0; ni < 2; ++ni) {
    const int cn = n0 + wn + ni * 16 + l15;
    const float bv = bias[cn];
    #pragma unroll
    for (int mi = 0; mi < 2; ++mi) {
      #pragma unroll
      for (int j = 0; j < 4; ++j) {
        const int rm = m0 + wm + mi * 16 + l16 * 4 + j;
        Cout[(size_t)rm * N + cn] = acc[mi][ni][j] + bv;
      }
    }
  }
}

// ---------------- sliding-window attention ----------------
// one block per (query-tile of 64, head); zero-padded K/V outside [0,S) matches reference.

__global__ __launch_bounds__(256) void attn_kernel(const __hip_bfloat16* __restrict__ qkv,
                                                   __hip_bfloat16* __restrict__ ctx){
  __shared__ unsigned int kbuf[KROWS * KPITCH_U];
  __shared__ unsigned int vbuf[KROWS * KPITCH_U];
  const int tid = threadIdx.x;
  const int h   = blockIdx.x & 15;
  const int qs0 = (blockIdx.x >> 4) * QT;

  // stage K/V window rows [qs0-16, qs0+79]
  #pragma unroll
  for (int it = 0; it < 3; ++it) {
    int c = tid + it * 256;            // 0..767
    int r = c >> 3, s8 = c & 7;
    int srow = qs0 - PAD + r;
    uint4 kv = make_uint4(0, 0, 0, 0), vv = make_uint4(0, 0, 0, 0);
    if ((unsigned)srow < (unsigned)S_LEN) {
      kv = ((const uint4*)(qkv + (size_t)srow * 3072 + h * 192 + 64))[s8];
      vv = ((const uint4*)(qkv + (size_t)srow * 3072 + h * 192 + 128))[s8];
    }
    *(uint4*)(kbuf + r * KPITCH_U + s8 * 4) = kv;
    *(uint4*)(vbuf + r * KPITCH_U + s8 * 4) = vv;
  }

  const int ql = tid >> 2, t4 = tid & 3;
  const uint4* qp = (const uint4*)(qkv + (size_t)(qs0 + ql) * 3072 + h * 192);
  float qf[64];
  #pragma unroll
  for (int c = 0; c < 8; ++c) {
    uint4 v = qp[c];
    qf[c*8+0] = bl(v.x); qf[c*8+1] = bh(v.x);
    qf[c*8+2] = bl(v.y); qf[c*8+3] = bh(v.y);
    qf[c*8+4] = bl(v.z); qf[c*8+5] = bh(v.z);
    qf[c*8+6] = bl(v.w); qf[c*8+7] = bh(v.w);
  }
  __syncthreads();

  float sc[9];
  #pragma unroll
  for (int j = 0; j < 9; ++j) sc[j] = 0.f;
  float mx = -1e30f;
  #pragma unroll
  for (int j = 0; j < 9; ++j) {
    int w = t4 + 4 * j;
    if (w < WIN) {
      int rw = ql + w;
      const uint4* kp = (const uint4*)(kbuf + rw * KPITCH_U);
      float d = 0.f;
      #pragma unroll
      for (int c = 0; c < 8; ++c) {
        uint4 kv = kp[c];
        d += qf[c*8+0]*bl(kv.x) + qf[c*8+1]*bh(kv.x)
           + qf[c*8+2]*bl(kv.y) + qf[c*8+3]*bh(kv.y)
           + qf[c*8+4]*bl(kv.z) + qf[c*8+5]*bh(kv.z)
           + qf[c*8+6]*bl(kv.w) + qf[c*8+7]*bh(kv.w);
      }
      sc[j] = d * 0.125f;
      mx = fmaxf(mx, sc[j]);
    }
  }
  mx = fmaxf(mx, __shfl_xor(mx, 1));
  mx = fmaxf(mx, __shfl_xor(mx, 2));
  float sum = 0.f;
  #pragma unroll
  for (int j = 0; j < 9; ++j) {
    int w = t4 + 4 * j;
    if (w < WIN) { sc[j] = __expf(sc[j] - mx); sum += sc[j]; }
  }
  sum += __shfl_xor(sum, 1);
  sum += __shfl_xor(sum, 2);
  const float inv = 1.0f / sum;
  #pragma unroll
  for (int j = 0; j < 9; ++j) sc[j] *= inv;

  float accd[16];
  #pragma unroll
  for (int i = 0; i < 16; ++i) accd[i] = 0.f;
  #pragma unroll
  for (int w = 0; w < WIN; ++w) {
    float wgt = __shfl(sc[w >> 2], ((tid & 63) & ~3) | (w & 3), 64);
    int rw = ql + w;
    const uint4* vp = (const uint4*)(vbuf + rw * KPITCH_U + t4 * 8);
    uint4 a = vp[0], b = vp[1];
    float vf[16];
    vf[0]=bl(a.x); vf[1]=bh(a.x); vf[2]=bl(a.y); vf[3]=bh(a.y);
    vf[4]=bl(a.z); vf[5]=bh(a.z); vf[6]=bl(a.w); vf[7]=bh(a.w);
    vf[8]=bl(b.x); vf[9]=bh(b.x); vf[10]=bl(b.y); vf[11]=bh(b.y);
    vf[12]=bl(b.z); vf[13]=bh(b.z); vf[14]=bl(b.w); vf[15]=bh(b.w);
    #pragma unroll
    for (int i = 0; i < 16; ++i) accd[i] += wgt * vf[i];
  }

  unsigned short* op = (unsigned short*)ctx + (size_t)(qs0 + ql) * 1024 + h * 64 + t4 * 16;
  uint4 o1, o2;
  o1.x = pack2(accd[0], accd[1]);  o1.y = pack2(accd[2], accd[3]);
  o1.z = pack2(accd[4], accd[5]);  o1.w = pack2(accd[6], accd[7]);
  o2.x = pack2(accd[8], accd[9]);  o2.y = pack2(accd[10], accd[11]);
  o2.z = pack2(accd[12], accd[13]); o2.w = pack2(accd[14], accd[15]);
  *(uint4*)op = o1;
  *((uint4*)op + 1) = o2;
}

// ---------------- launch ----------------

extern "C" void kernel_launch(void* const* d_in, const int* in_sizes, int n_in,
                              void* d_out, int out_size, void* d_ws, size_t ws_size,
                              hipStream_t stream)
{
  const float* x     = (const float*)d_in[0];
  const float* rot   = (const float*)d_in[1];
  const float* W_qkv = (const float*)d_in[2];
  const float* b_qkv = (const float*)d_in[3];
  const float* W_out = (const float*)d_in[4];
  const float* b_out = (const float*)d_in[5];
  float* out = (float*)d_out;

  char* ws = (char*)d_ws;
  __hip_bfloat16* xb   = (__hip_bfloat16*)(ws + 0);          //  8 MB
  __hip_bfloat16* Wt1  = (__hip_bfloat16*)(ws + 8388608);    //  6 MB  [3072][1024]
  __hip_bfloat16* Wt2  = (__hip_bfloat16*)(ws + 14680064);   //  2 MB  [1024][1024]
  __hip_bfloat16* qkvb = (__hip_bfloat16*)(ws + 16777216);   // 24 MB  [4096][3072]
  __hip_bfloat16* ctx  = (__hip_bfloat16*)(ws + 41943040);   //  8 MB  [4096][1024]
  float2* csq          = (float2*)(ws + 50331648);           //  1 MB  [4096][32] (cos,sin)

  prep_all<<<6656, 256, 0, stream>>>(rot, csq, x, xb, W_qkv, Wt1, W_out, Wt2);
  gemm_qkv_rope<<<dim3(3072 / 96, 4096 / 128), 256, 0, stream>>>(xb, Wt1, b_qkv, csq,
                                                                 (unsigned short*)qkvb, 4096, 3072, 1024);
  attn_kernel<<<64 * 16, 256, 0, stream>>>(qkvb, ctx);
  gemm_out64<<<dim3(1024 / 64, 4096 / 64), 256, 0, stream>>>(ctx, Wt2, b_out, out, 4096, 1024, 1024);
}